// Round 4
// baseline (5351.024 us; speedup 1.0000x reference)
//
#include <hip/hip_runtime.h>
#include <cstdint>
#include <cstddef>

// Problem constants
#define B_  4096
#define H_  300
#define T_  43
#define NC_ 80
#define HP  320      // padded hidden/input dim (300 -> 320)
#define ND  1280     // padded 4H per direction
#define NDD 2560     // both directions
#define KC  640      // concatenated K: [x_t (320) ; h_prev (320)]
#define TR  304      // hs per-t row length in f16 (300 + 4 zero pad, 16B aligned)
#define SB2 (T_ * TR) // hs per-(d,b) stride in f16 = 13072
#define BT  32       // batch tile per block
#define NBT (B_ / BT) // 128 batch tiles

// LDS layout (bytes). Rows padded to 328 f16 (656 B = 164 words, 164%32=4
// -> strided ds_read_b128 spreads over bank groups).
#define HROW 328
#define XS_OFF   0
#define H0_OFF   (XS_OFF + BT * HROW * 2)     // 20992
#define H1_OFF   (H0_OFF + BT * HROW * 2)     // 41984
#define C_OFF    (H1_OFF + BT * HROW * 2)     // 62976  (c[320][33] f32)
#define BIAS_OFF (C_OFF + 320 * 33 * 4)       // 105216 (bias[1280] f32)
#define LDS_TOTAL (BIAS_OFF + 1280 * 4)       // 110336

typedef _Float16 f16;
typedef _Float16 half8 __attribute__((ext_vector_type(8)));
typedef _Float16 half4 __attribute__((ext_vector_type(4)));
typedef float    f32x4 __attribute__((ext_vector_type(4)));

__device__ __forceinline__ float sigmoid_(float x) {
  return 1.f / (1.f + __expf(-x));
}
__device__ __forceinline__ float tanh_fast(float x) {
  x = fminf(fmaxf(x, -15.f), 15.f);
  float e = __expf(2.f * x);
  return (e - 1.f) / (e + 1.f);
}

// ---------------------------------------------------------------------------
// Weight packing, concatenated-K layout. Row index = d*1280 + 4*jh + g
// (gate-interleaved, order i,f,g,o). Wcat[2560][640]: cols 0..319 = Wih row
// (k < 300 real), cols 320..639 = Whh row. bias[2560] = b_ih + b_hh.
// ---------------------------------------------------------------------------
__global__ void prep_weights(const float* __restrict__ w_ih,
                             const float* __restrict__ w_hh,
                             const float* __restrict__ b_ih,
                             const float* __restrict__ b_hh,
                             f16* __restrict__ Wcat, float* __restrict__ bias) {
  int idx = blockIdx.x * 256 + threadIdx.x;
  const int total = NDD * KC;
  if (idx < total) {
    int row = idx / KC, k = idx % KC;
    int d = row / ND, n = row % ND;
    int jh = n >> 2, g = n & 3;
    int which = (k >= HP);           // 0 = Wih part, 1 = Whh part
    int kk = which ? (k - HP) : k;
    float v = 0.f;
    if (jh < H_ && kk < H_) {
      const float* W = which ? w_hh : w_ih;
      v = W[((size_t)d * 4 * H_ + g * H_ + jh) * H_ + kk];
    }
    Wcat[(size_t)row * KC + k] = (f16)v;
  }
  if (idx < NDD) {
    int d = idx / ND, n = idx % ND;
    int jh = n >> 2, g = n & 3;
    float v = 0.f;
    if (jh < H_)
      v = b_ih[d * 4 * H_ + g * H_ + jh] + b_hh[d * 4 * H_ + g * H_ + jh];
    bias[idx] = v;
  }
}

// ---------------------------------------------------------------------------
// x [B,H,T] fp32 -> xT[t*B+b][k] f16, k padded to 320 with zeros.
// ---------------------------------------------------------------------------
__global__ void prep_xT(const float* __restrict__ x, f16* __restrict__ xT) {
  __shared__ float tile[64][44];
  int b = blockIdx.x, ch = blockIdx.y;
  int h0 = ch * 64;
  for (int idx = threadIdx.x; idx < 64 * T_; idx += 256) {
    int hh = idx / T_, t = idx % T_;
    float v = 0.f;
    if (h0 + hh < H_) v = x[((size_t)b * H_ + h0 + hh) * T_ + t];
    tile[hh][t] = v;
  }
  __syncthreads();
  for (int idx = threadIdx.x; idx < 64 * T_; idx += 256) {
    int t = idx / 64, hh = idx % 64;
    xT[((size_t)t * B_ + b) * HP + h0 + hh] = (f16)tile[hh][t];
  }
}

// ---------------------------------------------------------------------------
// Weight K-slice load (10 row-tiles of 16) and MFMA helpers. KT is a
// compile-time K-step so all array indexing is static (no scratch).
// ---------------------------------------------------------------------------
template <int KT>
__device__ __forceinline__ void load_w(const f16* __restrict__ wr,
                                       half8 (&buf)[10]) {
#pragma unroll
  for (int i = 0; i < 10; i++)
    buf[i] = *(const half8*)(wr + (size_t)i * 16 * KC + KT * 32);
}

template <int KT>
__device__ __forceinline__ void do_k(const half8 (&af)[10],
                                     const f16* __restrict__ xs,
                                     const f16* __restrict__ hcur,
                                     int lr, int lq, f32x4 (&acc)[10][2]) {
  const f16* bslab = (KT < 10) ? xs : hcur;
  const int ko = ((KT < 10) ? KT * 32 : (KT - 10) * 32) + lq * 8;
  half8 bf[2];
#pragma unroll
  for (int j = 0; j < 2; j++)
    bf[j] = *(const half8*)(bslab + (j * 16 + lr) * HROW + ko);
#pragma unroll
  for (int i = 0; i < 10; i++)
#pragma unroll
    for (int j = 0; j < 2; j++)
      acc[i][j] = __builtin_amdgcn_mfma_f32_16x16x32_f16(af[i], bf[j],
                                                         acc[i][j], 0, 0, 0);
}

// ---------------------------------------------------------------------------
// Batch-sliced persistent LSTM: one block owns (direction d, 32 batch rows)
// for ALL 43 timesteps. No inter-block dependency. h ping-pongs in LDS, c in
// LDS — zero global state traffic. Weights stream L2 -> VGPR with an explicit
// 2-deep register double-buffer to hide L2 latency.
// 512 threads = 8 waves = 2 waves/SIMD; wave w owns gate rows [w*160,+160).
// grid (128 batch-tiles, 2 dirs) = 256 blocks = 1 per CU.
// __launch_bounds__(512, 1): ONE block/CU -> 2 waves/SIMD -> 256-VGPR cap.
// (Round 3 used min=2 which capped VGPRs at 128 and spilled 8 GB to scratch.)
// ---------------------------------------------------------------------------
__global__ __launch_bounds__(512, 1) void lstm_all(
    const f16* __restrict__ xT,     // [T][B][320]
    const f16* __restrict__ Wcat,   // [2560][640]
    const float* __restrict__ bias, // [2560]
    f16* __restrict__ hs) {         // [2][B][43][304]
  extern __shared__ __attribute__((aligned(16))) char smem[];
  f16* xs = (f16*)(smem + XS_OFF);
  f16* h0s = (f16*)(smem + H0_OFF);
  f16* h1s = (f16*)(smem + H1_OFF);
  float* cls = (float*)(smem + C_OFF);
  float* bl = (float*)(smem + BIAS_OFF);

  const int tid = threadIdx.x;
  const int wave = tid >> 6, lane = tid & 63;
  const int lr = lane & 15, lq = lane >> 4;
  const int bt = blockIdx.x, d = blockIdx.y;

  // ---- init: bias -> LDS, zero c, zero h0 ----
  for (int i = tid; i < 1280; i += 512) bl[i] = bias[d * ND + i];
  for (int i = tid; i < 320 * 33; i += 512) cls[i] = 0.f;
  for (int i = tid; i < BT * HROW; i += 512) h0s[i] = (f16)0.f;

  // x staging map: 1280 16B-chunks, up to 3 per thread (third valid tid<256).
  size_t goff[3];
  int doff[3];
#pragma unroll
  for (int p = 0; p < 3; ++p) {
    int idx = p * 512 + tid;
    int bb = (idx < 1280) ? idx / 40 : 0;
    int cc = (idx < 1280) ? idx % 40 : 0;
    goff[p] = ((size_t)(bt * BT + bb)) * HP + cc * 8;
    doff[p] = bb * HROW + cc * 8;
  }
  const bool p2ok = (tid < 256);

  // stage x_0
  {
    half8 x0[3];
    x0[0] = *(const half8*)(xT + goff[0]);
    x0[1] = *(const half8*)(xT + goff[1]);
    if (p2ok) x0[2] = *(const half8*)(xT + goff[2]);
    *(half8*)(xs + doff[0]) = x0[0];
    *(half8*)(xs + doff[1]) = x0[1];
    if (p2ok) *(half8*)(xs + doff[2]) = x0[2];
  }
  __syncthreads();

  // wave's weight base: rows [wave*160 ...), lane lr = row-in-tile, lq = k-quad
  const f16* wr = Wcat + ((size_t)d * ND + wave * 160 + lr) * KC + lq * 8;

  for (int t = 0; t < T_; ++t) {
    const f16* hcur = (t & 1) ? h1s : h0s;
    f16* hnxt = (t & 1) ? h0s : h1s;

    f32x4 acc[10][2];
#pragma unroll
    for (int i = 0; i < 10; i++)
#pragma unroll
      for (int j = 0; j < 2; j++) acc[i][j] = (f32x4){0.f, 0.f, 0.f, 0.f};

    half8 afA[10], afB[10];
    load_w<0>(wr, afA);

    // prefetch x_{t+1} to regs (latency hides under GEMM)
    half8 xn[3];
    if (t + 1 < T_) {
      const f16* xsrc = xT + (size_t)(t + 1) * B_ * HP;
      xn[0] = *(const half8*)(xsrc + goff[0]);
      xn[1] = *(const half8*)(xsrc + goff[1]);
      if (p2ok) xn[2] = *(const half8*)(xsrc + goff[2]);
    }

    // ---- GEMM z = Wcat @ [x_t ; h_prev]: 20 K-steps, 2-deep W double-buffer
#define PAIR(KA)                                   \
    load_w<(KA) + 1>(wr, afB);                     \
    do_k<(KA)>(afA, xs, hcur, lr, lq, acc);        \
    load_w<(KA) + 2>(wr, afA);                     \
    do_k<(KA) + 1>(afB, xs, hcur, lr, lq, acc);
    PAIR(0) PAIR(2) PAIR(4) PAIR(6) PAIR(8)
    PAIR(10) PAIR(12) PAIR(14) PAIR(16)
#undef PAIR
    load_w<19>(wr, afB);
    do_k<18>(afA, xs, hcur, lr, lq, acc);
    do_k<19>(afB, xs, hcur, lr, lq, acc);

    // ---- gate epilogue: c update (LDS), h_new -> hnxt ----
#pragma unroll
    for (int i = 0; i < 10; i++) {
      const int jh = wave * 40 + i * 4 + lq;  // 0..319
      const float4 b4 = *(const float4*)&bl[4 * jh];
#pragma unroll
      for (int j = 0; j < 2; j++) {
        const int b = j * 16 + lr;  // 0..31
        float* cp = &cls[jh * 33 + b];
        const float co = *cp;
        const float zi = acc[i][j][0] + b4.x;
        const float zf = acc[i][j][1] + b4.y;
        const float zg = acc[i][j][2] + b4.z;
        const float zo = acc[i][j][3] + b4.w;
        const float cn = sigmoid_(zf) * co + sigmoid_(zi) * tanh_fast(zg);
        *cp = cn;
        hnxt[b * HROW + jh] = (f16)(sigmoid_(zo) * tanh_fast(cn));
      }
    }
    __syncthreads();  // hnxt complete

    // ---- hs write-out: rows [b][304] contiguous from hnxt row b ----
    for (int idx = tid; idx < 32 * 38; idx += 512) {
      const int b = idx / 38, ch = idx % 38;  // 38 half8 chunks = 304 f16
      f16* dst = hs + ((size_t)d * B_ + bt * BT + b) * SB2 + t * TR;
      *(half8*)(dst + ch * 8) = *(const half8*)(hnxt + b * HROW + ch * 8);
    }
    // ---- commit prefetched x_{t+1} ----
    if (t + 1 < T_) {
      *(half8*)(xs + doff[0]) = xn[0];
      *(half8*)(xs + doff[1]) = xn[1];
      if (p2ok) *(half8*)(xs + doff[2]) = xn[2];
    }
    __syncthreads();
  }
}

// ---------------------------------------------------------------------------
// attn1: alpha[b][t] = softmax_t( sum_h tanh(hs0+hs1) * conv_w[h] ).
// Pure stream over hs; half4 loads (rows are 304-wide, zero-padded).
// ---------------------------------------------------------------------------
__global__ __launch_bounds__(256) void attn1(const f16* __restrict__ hs,
                                             const float* __restrict__ conv_w,
                                             float* __restrict__ alpha_g) {
  __shared__ float cw[TR];
  __shared__ float red[48];
  const int b = blockIdx.x, tid = threadIdx.x;
  const int wave = tid >> 6, lane = tid & 63;
  for (int k = tid; k < TR; k += 256) cw[k] = (k < H_) ? conv_w[k] : 0.f;
  __syncthreads();

  const half4* s0 = (const half4*)(hs + (size_t)b * SB2);
  const half4* s1 = (const half4*)(hs + (size_t)(B_ + b) * SB2);
  for (int t = wave; t < T_; t += 4) {
    const int base = t * (TR / 4);
    float p = 0.f;
    {
      half4 a = s0[base + lane], cc = s1[base + lane];
#pragma unroll
      for (int r = 0; r < 4; r++)
        p += tanh_fast((float)a[r] + (float)cc[r]) * cw[lane * 4 + r];
    }
    if (lane < 12) {
      half4 a = s0[base + 64 + lane], cc = s1[base + 64 + lane];
#pragma unroll
      for (int r = 0; r < 4; r++)
        p += tanh_fast((float)a[r] + (float)cc[r]) * cw[256 + lane * 4 + r];
    }
#pragma unroll
    for (int o = 32; o; o >>= 1) p += __shfl_down(p, o);
    if (lane == 0) red[t] = p;
  }
  __syncthreads();
  if (tid < 64) {
    float a = (tid < T_) ? red[tid] : -1e30f;
    float mx = a;
#pragma unroll
    for (int o = 32; o; o >>= 1) mx = fmaxf(mx, __shfl_xor(mx, o));
    float e = (tid < T_) ? __expf(a - mx) : 0.f;
    float s = e;
#pragma unroll
    for (int o = 32; o; o >>= 1) s += __shfl_xor(s, o);
    if (tid < T_) alpha_g[(size_t)b * 44 + tid] = e / s;
  }
}

// ---------------------------------------------------------------------------
// attn2: r[b][h] = sum_t hsum*alpha; hstar = tanh(r); logits; softmax.
// Thread-per-h accumulation, coalesced streaming.
// ---------------------------------------------------------------------------
__global__ __launch_bounds__(256) void attn2(const f16* __restrict__ hs,
                                             const float* __restrict__ alpha_g,
                                             const float* __restrict__ fc_w,
                                             const float* __restrict__ fc_b,
                                             float* __restrict__ out) {
  __shared__ float al[T_];
  __shared__ float hstar[TR];
  __shared__ float lg[NC_];
  const int b = blockIdx.x, tid = threadIdx.x;
  if (tid < T_) al[tid] = alpha_g[(size_t)b * 44 + tid];
  __syncthreads();

  const f16* s0 = hs + (size_t)b * SB2;
  const f16* s1 = hs + (size_t)(B_ + b) * SB2;
  float r0 = 0.f, r1 = 0.f;
  for (int t = 0; t < T_; t++) {
    const float a = al[t];
    r0 += ((float)s0[t * TR + tid] + (float)s1[t * TR + tid]) * a;
    if (tid < 48)
      r1 += ((float)s0[t * TR + 256 + tid] + (float)s1[t * TR + 256 + tid]) * a;
  }
  hstar[tid] = tanh_fast(r0);
  if (tid < 48) hstar[256 + tid] = tanh_fast(r1);
  __syncthreads();

  const int wave = tid >> 6, lane = tid & 63;
  for (int cls = wave; cls < NC_; cls += 4) {
    float p = 0.f;
    for (int k = lane; k < H_; k += 64) p += hstar[k] * fc_w[(size_t)cls * H_ + k];
#pragma unroll
    for (int o = 32; o; o >>= 1) p += __shfl_down(p, o);
    if (lane == 0) lg[cls] = p + fc_b[cls];
  }
  __syncthreads();
  if (tid < 64) {
    float a0 = (tid < 40) ? lg[tid] : -1e30f;
    float a1 = (tid < 40) ? lg[tid + 40] : -1e30f;
    float mx = fmaxf(a0, a1);
#pragma unroll
    for (int o = 32; o; o >>= 1) mx = fmaxf(mx, __shfl_xor(mx, o));
    float e0 = (tid < 40) ? __expf(a0 - mx) : 0.f;
    float e1 = (tid < 40) ? __expf(a1 - mx) : 0.f;
    float s = e0 + e1;
#pragma unroll
    for (int o = 32; o; o >>= 1) s += __shfl_xor(s, o);
    if (tid < 40) {
      out[(size_t)b * NC_ + tid] = e0 / s;
      out[(size_t)b * NC_ + tid + 40] = e1 / s;
    }
  }
}

// ---------------------------------------------------------------------------
extern "C" void kernel_launch(void* const* d_in, const int* in_sizes, int n_in,
                              void* d_out, int out_size, void* d_ws, size_t ws_size,
                              hipStream_t stream) {
  const float* x      = (const float*)d_in[0];
  const float* w_ih   = (const float*)d_in[1];
  const float* w_hh   = (const float*)d_in[2];
  const float* b_ih   = (const float*)d_in[3];
  const float* b_hh   = (const float*)d_in[4];
  const float* conv_w = (const float*)d_in[5];
  const float* fc_w   = (const float*)d_in[6];
  const float* fc_b   = (const float*)d_in[7];
  float* out = (float*)d_out;

  // Workspace carve (~331 MB)
  char* p = (char*)d_ws;
  f16* Wcat = (f16*)p;  p += (size_t)NDD * KC * sizeof(f16);        // 3.3 MB
  float* bias = (float*)p; p += (size_t)NDD * sizeof(float);
  p = (char*)(((uintptr_t)p + 255) & ~(uintptr_t)255);
  f16* xT = (f16*)p;    p += (size_t)T_ * B_ * HP * sizeof(f16);    // 112.7 MB
  f16* hs = (f16*)p;    p += (size_t)2 * B_ * SB2 * sizeof(f16);    // 214.2 MB
  float* alpha_g = (float*)p; p += (size_t)B_ * 44 * sizeof(float); // 0.72 MB

  prep_weights<<<(NDD * KC + 255) / 256, 256, 0, stream>>>(
      w_ih, w_hh, b_ih, b_hh, Wcat, bias);
  prep_xT<<<dim3(B_, 5), 256, 0, stream>>>(x, xT);

  lstm_all<<<dim3(NBT, 2), 512, LDS_TOTAL, stream>>>(xT, Wcat, bias, hs);

  attn1<<<B_, 256, 0, stream>>>(hs, conv_w, alpha_g);
  attn2<<<B_, 256, 0, stream>>>(hs, alpha_g, fc_w, fc_b, out);
}

// Round 5
// 4571.378 us; speedup vs baseline: 1.1705x; 1.1705x over previous
//
#include <hip/hip_runtime.h>
#include <cstdint>
#include <cstddef>

// Problem constants
#define B_  4096
#define H_  300
#define T_  43
#define NC_ 80
#define HP  320      // padded hidden/input dim (300 -> 320)
#define ND  1280     // padded 4H per direction
#define NDD 2560     // both directions
#define KC  640      // concatenated K: [x_t (320) ; h_prev (320)]
#define TR  304      // hs per-t row length in f16 (300 + 4 zero pad, 16B aligned)
#define SB2 (T_ * TR) // hs per-(d,b) stride in f16 = 13072
#define BT  32       // batch tile per block
#define NBT (B_ / BT) // 128 batch tiles

// LDS layout (bytes). Rows padded to 328 f16 (656 B = 164 words, 164%32=4
// -> 16 lanes spread 2/bank = conflict-free per m136).
#define HROW 328
#define XS_OFF   0
#define H0_OFF   (XS_OFF + BT * HROW * 2)     // 20992
#define H1_OFF   (H0_OFF + BT * HROW * 2)     // 41984
#define BIAS_OFF (H1_OFF + BT * HROW * 2)     // 62976 (bias[1280] f32)
#define LDS_TOTAL (BIAS_OFF + 1280 * 4)       // 68096

typedef _Float16 f16;
typedef _Float16 half8 __attribute__((ext_vector_type(8)));
typedef _Float16 half4 __attribute__((ext_vector_type(4)));
typedef float    f32x4 __attribute__((ext_vector_type(4)));

__device__ __forceinline__ float sigmoid_(float x) {
  return 1.f / (1.f + __expf(-x));
}
__device__ __forceinline__ float tanh_fast(float x) {
  x = fminf(fmaxf(x, -15.f), 15.f);
  float e = __expf(2.f * x);
  return (e - 1.f) / (e + 1.f);
}

// ---------------------------------------------------------------------------
// Weight packing, concatenated-K layout. Row index = d*1280 + 4*jh + g
// (gate-interleaved, order i,f,g,o). Wcat[2560][640]: cols 0..319 = Wih row
// (k < 300 real), cols 320..639 = Whh row. bias[2560] = b_ih + b_hh.
// ---------------------------------------------------------------------------
__global__ void prep_weights(const float* __restrict__ w_ih,
                             const float* __restrict__ w_hh,
                             const float* __restrict__ b_ih,
                             const float* __restrict__ b_hh,
                             f16* __restrict__ Wcat, float* __restrict__ bias) {
  int idx = blockIdx.x * 256 + threadIdx.x;
  const int total = NDD * KC;
  if (idx < total) {
    int row = idx / KC, k = idx % KC;
    int d = row / ND, n = row % ND;
    int jh = n >> 2, g = n & 3;
    int which = (k >= HP);           // 0 = Wih part, 1 = Whh part
    int kk = which ? (k - HP) : k;
    float v = 0.f;
    if (jh < H_ && kk < H_) {
      const float* W = which ? w_hh : w_ih;
      v = W[((size_t)d * 4 * H_ + g * H_ + jh) * H_ + kk];
    }
    Wcat[(size_t)row * KC + k] = (f16)v;
  }
  if (idx < NDD) {
    int d = idx / ND, n = idx % ND;
    int jh = n >> 2, g = n & 3;
    float v = 0.f;
    if (jh < H_)
      v = b_ih[d * 4 * H_ + g * H_ + jh] + b_hh[d * 4 * H_ + g * H_ + jh];
    bias[idx] = v;
  }
}

// ---------------------------------------------------------------------------
// x [B,H,T] fp32 -> xT[t*B+b][k] f16, k padded to 320 with zeros.
// ---------------------------------------------------------------------------
__global__ void prep_xT(const float* __restrict__ x, f16* __restrict__ xT) {
  __shared__ float tile[64][44];
  int b = blockIdx.x, ch = blockIdx.y;
  int h0 = ch * 64;
  for (int idx = threadIdx.x; idx < 64 * T_; idx += 256) {
    int hh = idx / T_, t = idx % T_;
    float v = 0.f;
    if (h0 + hh < H_) v = x[((size_t)b * H_ + h0 + hh) * T_ + t];
    tile[hh][t] = v;
  }
  __syncthreads();
  for (int idx = threadIdx.x; idx < 64 * T_; idx += 256) {
    int t = idx / 64, hh = idx % 64;
    xT[((size_t)t * B_ + b) * HP + h0 + hh] = (f16)tile[hh][t];
  }
}

// ---------------------------------------------------------------------------
// Weight K-slice load (5 row-tiles of 16 per wave) and MFMA step. KT is a
// compile-time K-step so all indexing is static (no scratch).
// ---------------------------------------------------------------------------
template <int KT>
__device__ __forceinline__ void load_w5(const f16* __restrict__ wr,
                                        half8 (&buf)[5]) {
#pragma unroll
  for (int i = 0; i < 5; i++)
    buf[i] = *(const half8*)(wr + (size_t)i * 16 * KC + KT * 32);
}

template <int KT>
__device__ __forceinline__ void do_k5(const half8 (&af)[5],
                                      const f16* __restrict__ xs,
                                      const f16* __restrict__ hcur,
                                      int lr, int lq, f32x4 (&acc)[5][2]) {
  const f16* bslab = (KT < 10) ? xs : hcur;
  const int ko = ((KT < 10) ? KT * 32 : (KT - 10) * 32) + lq * 8;
  half8 bf[2];
#pragma unroll
  for (int j = 0; j < 2; j++)
    bf[j] = *(const half8*)(bslab + (j * 16 + lr) * HROW + ko);
#pragma unroll
  for (int i = 0; i < 5; i++)
#pragma unroll
    for (int j = 0; j < 2; j++)
      acc[i][j] = __builtin_amdgcn_mfma_f32_16x16x32_f16(af[i], bf[j],
                                                         acc[i][j], 0, 0, 0);
}

// ---------------------------------------------------------------------------
// Batch-sliced persistent LSTM: one block owns (direction d, 32 batch rows)
// for ALL 43 timesteps. No inter-block dependency. h ping-pongs in LDS; c in
// REGISTERS (mapping is static per lane). Weights stream L2 -> VGPR with a
// one-K-step register double-buffer.
// 1024 threads = 16 waves = 4 waves/SIMD (TLP for latency hiding); wave w
// owns gate rows [w*80, w*80+80) -> acc[5][2] (40) + creg[5][2] (10) +
// W dbuf 2x5 (40) + bf/xn/addr ~= 90 arch VGPRs: fits the 128 cap that a
// 1024-thread block imposes (4 waves/SIMD). Rounds 3/4 spilled 8 GB because
// the 512-thread layout needed ~140 arch VGPRs against the same cap.
// XCD direction-grouping: flat grid 256; xcd = id&7; xcd 0..3 -> d=0,
// 4..7 -> d=1, so each XCD caches only its 1.64 MB weight set (L2-resident).
// ---------------------------------------------------------------------------
__global__ __launch_bounds__(1024, 1) void lstm_all(
    const f16* __restrict__ xT,     // [T][B][320]
    const f16* __restrict__ Wcat,   // [2560][640]
    const float* __restrict__ bias, // [2560]
    f16* __restrict__ hs) {         // [2][B][43][304]
  extern __shared__ __attribute__((aligned(16))) char smem[];
  f16* xs = (f16*)(smem + XS_OFF);
  f16* h0s = (f16*)(smem + H0_OFF);
  f16* h1s = (f16*)(smem + H1_OFF);
  float* bl = (float*)(smem + BIAS_OFF);

  const int tid = threadIdx.x;
  const int wave = tid >> 6, lane = tid & 63;
  const int lr = lane & 15, lq = lane >> 4;

  // XCD-grouped decode: all blocks on one XCD share a direction.
  const int id = blockIdx.x;
  const int xcd = id & 7, slot = id >> 3;
  const int d = xcd >> 2;
  const int bt = (xcd & 3) * 32 + slot;   // 0..127

  // ---- init: bias -> LDS, zero h0 ----
  for (int i = tid; i < 1280; i += 1024) bl[i] = bias[d * ND + i];
  for (int i = tid; i < BT * HROW; i += 1024) h0s[i] = (f16)0.f;

  // x staging map: 1280 16B-chunks; chunk tid for all, chunk 1024+tid (tid<256)
  size_t goff0, goff1;
  int doff0, doff1;
  {
    int bb = tid / 40, cc = tid % 40;
    goff0 = ((size_t)(bt * BT + bb)) * HP + cc * 8;
    doff0 = bb * HROW + cc * 8;
    int idx1 = 1024 + tid;
    int b1 = (idx1 < 1280) ? idx1 / 40 : 0, c1 = (idx1 < 1280) ? idx1 % 40 : 0;
    goff1 = ((size_t)(bt * BT + b1)) * HP + c1 * 8;
    doff1 = b1 * HROW + c1 * 8;
  }
  const bool p1ok = (tid < 256);

  // stage x_0
  {
    half8 a0 = *(const half8*)(xT + goff0);
    half8 a1;
    if (p1ok) a1 = *(const half8*)(xT + goff1);
    *(half8*)(xs + doff0) = a0;
    if (p1ok) *(half8*)(xs + doff1) = a1;
  }
  __syncthreads();

  // wave's weight base: rows [wave*80 ...), lane lr = row-in-tile, lq = k-quad
  const f16* wr = Wcat + ((size_t)d * ND + wave * 80 + lr) * KC + lq * 8;

  float creg[5][2];
#pragma unroll
  for (int i = 0; i < 5; i++) { creg[i][0] = 0.f; creg[i][1] = 0.f; }

  for (int t = 0; t < T_; ++t) {
    const f16* hcur = (t & 1) ? h1s : h0s;
    f16* hnxt = (t & 1) ? h0s : h1s;

    f32x4 acc[5][2];
#pragma unroll
    for (int i = 0; i < 5; i++)
#pragma unroll
      for (int j = 0; j < 2; j++) acc[i][j] = (f32x4){0.f, 0.f, 0.f, 0.f};

    half8 afA[5], afB[5];
    load_w5<0>(wr, afA);

    // prefetch x_{t+1} to regs (latency hides under GEMM)
    half8 xn0, xn1;
    if (t + 1 < T_) {
      const f16* xsrc = xT + (size_t)(t + 1) * B_ * HP;
      xn0 = *(const half8*)(xsrc + goff0);
      if (p1ok) xn1 = *(const half8*)(xsrc + goff1);
    }

    // ---- GEMM z = Wcat @ [x_t ; h_prev]: 20 K-steps, 1-K-step W dbuf ----
#define PAIR(KA)                                   \
    load_w5<(KA) + 1>(wr, afB);                    \
    do_k5<(KA)>(afA, xs, hcur, lr, lq, acc);       \
    load_w5<(KA) + 2>(wr, afA);                    \
    do_k5<(KA) + 1>(afB, xs, hcur, lr, lq, acc);
    PAIR(0) PAIR(2) PAIR(4) PAIR(6) PAIR(8)
    PAIR(10) PAIR(12) PAIR(14) PAIR(16)
#undef PAIR
    load_w5<19>(wr, afB);
    do_k5<18>(afA, xs, hcur, lr, lq, acc);
    do_k5<19>(afB, xs, hcur, lr, lq, acc);

    // ---- gate epilogue: c in registers, h_new -> hnxt (LDS) ----
#pragma unroll
    for (int i = 0; i < 5; i++) {
      const int jh = wave * 20 + i * 4 + lq;  // 0..319
      const float4 b4 = *(const float4*)&bl[4 * jh];
#pragma unroll
      for (int j = 0; j < 2; j++) {
        const int b = j * 16 + lr;  // 0..31
        const float zi = acc[i][j][0] + b4.x;
        const float zf = acc[i][j][1] + b4.y;
        const float zg = acc[i][j][2] + b4.z;
        const float zo = acc[i][j][3] + b4.w;
        const float cn =
            sigmoid_(zf) * creg[i][j] + sigmoid_(zi) * tanh_fast(zg);
        creg[i][j] = cn;  // pad rows (jh>=300): all-zero weights -> stays 0
        hnxt[b * HROW + jh] = (f16)(sigmoid_(zo) * tanh_fast(cn));
      }
    }
    __syncthreads();  // hnxt complete

    // ---- hs write-out: rows [b][304] contiguous from hnxt row b ----
    for (int idx = tid; idx < 32 * 38; idx += 1024) {
      const int b = idx / 38, ch = idx % 38;  // 38 half8 chunks = 304 f16
      f16* dst = hs + ((size_t)d * B_ + bt * BT + b) * SB2 + t * TR;
      *(half8*)(dst + ch * 8) = *(const half8*)(hnxt + b * HROW + ch * 8);
    }
    // ---- commit prefetched x_{t+1} ----
    if (t + 1 < T_) {
      *(half8*)(xs + doff0) = xn0;
      if (p1ok) *(half8*)(xs + doff1) = xn1;
    }
    __syncthreads();
  }
}

// ---------------------------------------------------------------------------
// attn1: alpha[b][t] = softmax_t( sum_h tanh(hs0+hs1) * conv_w[h] ).
// Pure stream over hs; half4 loads (rows are 304-wide, zero-padded).
// ---------------------------------------------------------------------------
__global__ __launch_bounds__(256) void attn1(const f16* __restrict__ hs,
                                             const float* __restrict__ conv_w,
                                             float* __restrict__ alpha_g) {
  __shared__ float cw[TR];
  __shared__ float red[48];
  const int b = blockIdx.x, tid = threadIdx.x;
  const int wave = tid >> 6, lane = tid & 63;
  for (int k = tid; k < TR; k += 256) cw[k] = (k < H_) ? conv_w[k] : 0.f;
  __syncthreads();

  const half4* s0 = (const half4*)(hs + (size_t)b * SB2);
  const half4* s1 = (const half4*)(hs + (size_t)(B_ + b) * SB2);
  for (int t = wave; t < T_; t += 4) {
    const int base = t * (TR / 4);
    float p = 0.f;
    {
      half4 a = s0[base + lane], cc = s1[base + lane];
#pragma unroll
      for (int r = 0; r < 4; r++)
        p += tanh_fast((float)a[r] + (float)cc[r]) * cw[lane * 4 + r];
    }
    if (lane < 12) {
      half4 a = s0[base + 64 + lane], cc = s1[base + 64 + lane];
#pragma unroll
      for (int r = 0; r < 4; r++)
        p += tanh_fast((float)a[r] + (float)cc[r]) * cw[256 + lane * 4 + r];
    }
#pragma unroll
    for (int o = 32; o; o >>= 1) p += __shfl_down(p, o);
    if (lane == 0) red[t] = p;
  }
  __syncthreads();
  if (tid < 64) {
    float a = (tid < T_) ? red[tid] : -1e30f;
    float mx = a;
#pragma unroll
    for (int o = 32; o; o >>= 1) mx = fmaxf(mx, __shfl_xor(mx, o));
    float e = (tid < T_) ? __expf(a - mx) : 0.f;
    float s = e;
#pragma unroll
    for (int o = 32; o; o >>= 1) s += __shfl_xor(s, o);
    if (tid < T_) alpha_g[(size_t)b * 44 + tid] = e / s;
  }
}

// ---------------------------------------------------------------------------
// attn2: r[b][h] = sum_t hsum*alpha; hstar = tanh(r); logits; softmax.
// Thread-per-h accumulation, coalesced streaming.
// ---------------------------------------------------------------------------
__global__ __launch_bounds__(256) void attn2(const f16* __restrict__ hs,
                                             const float* __restrict__ alpha_g,
                                             const float* __restrict__ fc_w,
                                             const float* __restrict__ fc_b,
                                             float* __restrict__ out) {
  __shared__ float al[T_];
  __shared__ float hstar[TR];
  __shared__ float lg[NC_];
  const int b = blockIdx.x, tid = threadIdx.x;
  if (tid < T_) al[tid] = alpha_g[(size_t)b * 44 + tid];
  __syncthreads();

  const f16* s0 = hs + (size_t)b * SB2;
  const f16* s1 = hs + (size_t)(B_ + b) * SB2;
  float r0 = 0.f, r1 = 0.f;
  for (int t = 0; t < T_; t++) {
    const float a = al[t];
    r0 += ((float)s0[t * TR + tid] + (float)s1[t * TR + tid]) * a;
    if (tid < 48)
      r1 += ((float)s0[t * TR + 256 + tid] + (float)s1[t * TR + 256 + tid]) * a;
  }
  hstar[tid] = tanh_fast(r0);
  if (tid < 48) hstar[256 + tid] = tanh_fast(r1);
  __syncthreads();

  const int wave = tid >> 6, lane = tid & 63;
  for (int cls = wave; cls < NC_; cls += 4) {
    float p = 0.f;
    for (int k = lane; k < H_; k += 64) p += hstar[k] * fc_w[(size_t)cls * H_ + k];
#pragma unroll
    for (int o = 32; o; o >>= 1) p += __shfl_down(p, o);
    if (lane == 0) lg[cls] = p + fc_b[cls];
  }
  __syncthreads();
  if (tid < 64) {
    float a0 = (tid < 40) ? lg[tid] : -1e30f;
    float a1 = (tid < 40) ? lg[tid + 40] : -1e30f;
    float mx = fmaxf(a0, a1);
#pragma unroll
    for (int o = 32; o; o >>= 1) mx = fmaxf(mx, __shfl_xor(mx, o));
    float e0 = (tid < 40) ? __expf(a0 - mx) : 0.f;
    float e1 = (tid < 40) ? __expf(a1 - mx) : 0.f;
    float s = e0 + e1;
#pragma unroll
    for (int o = 32; o; o >>= 1) s += __shfl_xor(s, o);
    if (tid < 40) {
      out[(size_t)b * NC_ + tid] = e0 / s;
      out[(size_t)b * NC_ + tid + 40] = e1 / s;
    }
  }
}

// ---------------------------------------------------------------------------
extern "C" void kernel_launch(void* const* d_in, const int* in_sizes, int n_in,
                              void* d_out, int out_size, void* d_ws, size_t ws_size,
                              hipStream_t stream) {
  const float* x      = (const float*)d_in[0];
  const float* w_ih   = (const float*)d_in[1];
  const float* w_hh   = (const float*)d_in[2];
  const float* b_ih   = (const float*)d_in[3];
  const float* b_hh   = (const float*)d_in[4];
  const float* conv_w = (const float*)d_in[5];
  const float* fc_w   = (const float*)d_in[6];
  const float* fc_b   = (const float*)d_in[7];
  float* out = (float*)d_out;

  // Workspace carve (~331 MB)
  char* p = (char*)d_ws;
  f16* Wcat = (f16*)p;  p += (size_t)NDD * KC * sizeof(f16);        // 3.3 MB
  float* bias = (float*)p; p += (size_t)NDD * sizeof(float);
  p = (char*)(((uintptr_t)p + 255) & ~(uintptr_t)255);
  f16* xT = (f16*)p;    p += (size_t)T_ * B_ * HP * sizeof(f16);    // 112.7 MB
  f16* hs = (f16*)p;    p += (size_t)2 * B_ * SB2 * sizeof(f16);    // 214.2 MB
  float* alpha_g = (float*)p; p += (size_t)B_ * 44 * sizeof(float); // 0.72 MB

  prep_weights<<<(NDD * KC + 255) / 256, 256, 0, stream>>>(
      w_ih, w_hh, b_ih, b_hh, Wcat, bias);
  prep_xT<<<dim3(B_, 5), 256, 0, stream>>>(x, xT);

  lstm_all<<<256, 1024, LDS_TOTAL, stream>>>(xT, Wcat, bias, hs);

  attn1<<<B_, 256, 0, stream>>>(hs, conv_w, alpha_g);
  attn2<<<B_, 256, 0, stream>>>(hs, alpha_g, fc_w, fc_b, out);
}

// Round 6
// 2786.978 us; speedup vs baseline: 1.9200x; 1.6403x over previous
//
#include <hip/hip_runtime.h>
#include <cstdint>
#include <cstddef>

// Problem constants
#define B_  4096
#define H_  300
#define T_  43
#define NC_ 80
#define HP  320      // padded hidden/input dim (300 -> 320)
#define ND  1280     // padded 4H per direction
#define NDD 2560     // both directions
#define KC  640      // concatenated K: [x_t (320) ; h_prev (320)]
#define TR  304      // hs per-t row length in f16 (300 + 4 zero pad, 16B aligned)
#define SB2 (T_ * TR) // hs per-(d,b) stride in f16 = 13072
#define BT  32       // batch tile per block

// LDS layout (bytes). Rows padded to 328 f16 (656 B -> bank spread).
#define HROW 328
#define XS_OFF   0
#define H0_OFF   (XS_OFF + BT * HROW * 2)     // 20992
#define H1_OFF   (H0_OFF + BT * HROW * 2)     // 41984
#define C_OFF    (H1_OFF + BT * HROW * 2)     // 62976  (c[320][33] f32)
#define BIAS_OFF (C_OFF + 320 * 33 * 4)       // 105216 (bias[1280] f32)
#define LDS_TOTAL (BIAS_OFF + 1280 * 4)       // 110336

typedef _Float16 f16;
typedef _Float16 half8 __attribute__((ext_vector_type(8)));
typedef _Float16 half4 __attribute__((ext_vector_type(4)));
typedef float    f32x4 __attribute__((ext_vector_type(4)));

__device__ __forceinline__ float sigmoid_(float x) {
  return 1.f / (1.f + __expf(-x));
}
__device__ __forceinline__ float tanh_fast(float x) {
  x = fminf(fmaxf(x, -15.f), 15.f);
  float e = __expf(2.f * x);
  return (e - 1.f) / (e + 1.f);
}

// ---------------------------------------------------------------------------
// Weight packing, concatenated-K layout. Row index = d*1280 + 4*jh + g
// (gate-interleaved, order i,f,g,o). Wcat[2560][640]: cols 0..319 = Wih row
// (k < 300 real), cols 320..639 = Whh row. bias[2560] = b_ih + b_hh.
// ---------------------------------------------------------------------------
__global__ void prep_weights(const float* __restrict__ w_ih,
                             const float* __restrict__ w_hh,
                             const float* __restrict__ b_ih,
                             const float* __restrict__ b_hh,
                             f16* __restrict__ Wcat, float* __restrict__ bias) {
  int idx = blockIdx.x * 256 + threadIdx.x;
  const int total = NDD * KC;
  if (idx < total) {
    int row = idx / KC, k = idx % KC;
    int d = row / ND, n = row % ND;
    int jh = n >> 2, g = n & 3;
    int which = (k >= HP);           // 0 = Wih part, 1 = Whh part
    int kk = which ? (k - HP) : k;
    float v = 0.f;
    if (jh < H_ && kk < H_) {
      const float* W = which ? w_hh : w_ih;
      v = W[((size_t)d * 4 * H_ + g * H_ + jh) * H_ + kk];
    }
    Wcat[(size_t)row * KC + k] = (f16)v;
  }
  if (idx < NDD) {
    int d = idx / ND, n = idx % ND;
    int jh = n >> 2, g = n & 3;
    float v = 0.f;
    if (jh < H_)
      v = b_ih[d * 4 * H_ + g * H_ + jh] + b_hh[d * 4 * H_ + g * H_ + jh];
    bias[idx] = v;
  }
}

// ---------------------------------------------------------------------------
// x [B,H,T] fp32 -> xT[t*B+b][k] f16, k padded to 320 with zeros.
// ---------------------------------------------------------------------------
__global__ void prep_xT(const float* __restrict__ x, f16* __restrict__ xT) {
  __shared__ float tile[64][44];
  int b = blockIdx.x, ch = blockIdx.y;
  int h0 = ch * 64;
  for (int idx = threadIdx.x; idx < 64 * T_; idx += 256) {
    int hh = idx / T_, t = idx % T_;
    float v = 0.f;
    if (h0 + hh < H_) v = x[((size_t)b * H_ + h0 + hh) * T_ + t];
    tile[hh][t] = v;
  }
  __syncthreads();
  for (int idx = threadIdx.x; idx < 64 * T_; idx += 256) {
    int t = idx / 64, hh = idx % 64;
    xT[((size_t)t * B_ + b) * HP + h0 + hh] = (f16)tile[hh][t];
  }
}

// ---------------------------------------------------------------------------
// K-step: MFMAs consume A buffer K%5, then refill it for K+5 (the last 5
// K-steps refill for the NEXT chunk's K=0..4 via wrn, so the load pipeline
// never drains across chunk/timestep boundaries). All register-array indices
// are compile-time constants.
// ---------------------------------------------------------------------------
template <int K>
__device__ __forceinline__ void kstep(const f16* __restrict__ wrm,
                                      const f16* __restrict__ wrn,
                                      half8 (&Ab)[5][4],
                                      const half8 (&bfx)[20][2],
                                      f32x4 (&acc)[4][2]) {
#pragma unroll
  for (int i = 0; i < 4; i++) {
    acc[i][0] = __builtin_amdgcn_mfma_f32_16x16x32_f16(Ab[K % 5][i], bfx[K][0],
                                                       acc[i][0], 0, 0, 0);
    acc[i][1] = __builtin_amdgcn_mfma_f32_16x16x32_f16(Ab[K % 5][i], bfx[K][1],
                                                       acc[i][1], 0, 0, 0);
  }
  if constexpr (K + 5 < 20) {
#pragma unroll
    for (int i = 0; i < 4; i++)
      Ab[K % 5][i] =
          *(const half8*)(wrm + (size_t)i * 16 * KC + (K + 5) * 32);
  } else {
#pragma unroll
    for (int i = 0; i < 4; i++)
      Ab[K % 5][i] =
          *(const half8*)(wrn + (size_t)i * 16 * KC + (K + 5 - 20) * 32);
  }
}

// ---------------------------------------------------------------------------
// Batch-sliced persistent LSTM: one block owns (direction d, 32 batch rows)
// for ALL 43 timesteps. No inter-block dependency. h ping-pongs in LDS, c in
// LDS. Weights stream L2 -> VGPR.
// 256 threads = 4 waves = 1 wave/SIMD: 512-VGPR cap -> the deep register
// pipeline below CANNOT spill (rounds 3-5 all spilled at >=2 waves/SIMD).
// Latency hiding is pure ILP:
//   - bfx[20][2] (160 v): all B-fragments for the step, loaded once (they
//     are chunk-invariant), so the inner loop has NO LDS reads.
//   - Ab[5][4] (80 v): 5-deep rolling A-buffer -> 20 outstanding 1KB loads.
// grid flat 256 = 1 block/CU; xcd=id&7 groups directions per-XCD so each
// XCD caches only its 1.64 MB weight set in L2.
// ---------------------------------------------------------------------------
__global__ __launch_bounds__(256, 1) void lstm_all(
    const f16* __restrict__ xT,     // [T][B][320]
    const f16* __restrict__ Wcat,   // [2560][640]
    const float* __restrict__ bias, // [2560]
    f16* __restrict__ hs) {         // [2][B][43][304]
  extern __shared__ __attribute__((aligned(16))) char smem[];
  f16* xs = (f16*)(smem + XS_OFF);
  f16* h0s = (f16*)(smem + H0_OFF);
  f16* h1s = (f16*)(smem + H1_OFF);
  float* cls = (float*)(smem + C_OFF);
  float* bl = (float*)(smem + BIAS_OFF);

  const int tid = threadIdx.x;
  const int wave = tid >> 6, lane = tid & 63;
  const int lr = lane & 15, lq = lane >> 4;
  const int kq = lq << 3;

  // XCD-grouped decode: all blocks on one XCD share a direction.
  const int id = blockIdx.x;
  const int xcd = id & 7, slot = id >> 3;
  const int d = xcd >> 2;
  const int bt = (xcd & 3) * 32 + slot;   // 0..127

  // ---- init: bias -> LDS, zero c, zero h0 ----
  for (int i = tid; i < 1280; i += 256) bl[i] = bias[d * ND + i];
  for (int i = tid; i < 320 * 33; i += 256) cls[i] = 0.f;
  for (int i = tid; i < BT * HROW; i += 256) h0s[i] = (f16)0.f;

  // x staging map: 1280 16B-chunks = 5 per thread.
  size_t goff[5];
  int doff[5];
#pragma unroll
  for (int p = 0; p < 5; ++p) {
    int idx = p * 256 + tid;
    int bb = idx / 40, cc = idx % 40;     // 40 chunks of 16B per 320-f16 row
    goff[p] = ((size_t)(bt * BT + bb)) * HP + cc * 8;
    doff[p] = bb * HROW + cc * 8;
  }

  // stage x_0
  {
    half8 x0[5];
#pragma unroll
    for (int p = 0; p < 5; ++p) x0[p] = *(const half8*)(xT + goff[p]);
#pragma unroll
    for (int p = 0; p < 5; ++p) *(half8*)(xs + doff[p]) = x0[p];
  }
  __syncthreads();

  // wave's weight base: chunk m covers rows m*256 + wave*64 + i*16 + lr.
  const f16* wr0 = Wcat + ((size_t)d * ND + wave * 64 + lr) * KC + kq;

  // A-pipeline prologue: chunk 0, K=0..4 (stays primed across t).
  half8 Ab[5][4];
#pragma unroll
  for (int k = 0; k < 5; k++)
#pragma unroll
    for (int i = 0; i < 4; i++)
      Ab[k][i] = *(const half8*)(wr0 + (size_t)i * 16 * KC + k * 32);

  for (int t = 0; t < T_; ++t) {
    const f16* hcur = (t & 1) ? h1s : h0s;
    f16* hnxt = (t & 1) ? h0s : h1s;

    // prefetch x_{t+1} to regs (latency hides under GEMM)
    half8 xn[5];
    if (t + 1 < T_) {
      const f16* xsrc = xT + (size_t)(t + 1) * B_ * HP;
#pragma unroll
      for (int p = 0; p < 5; ++p) xn[p] = *(const half8*)(xsrc + goff[p]);
    }

    // ---- B-fragments for ALL 20 K-steps (chunk-invariant): 160 VGPRs ----
    half8 bfx[20][2];
#pragma unroll
    for (int K = 0; K < 20; ++K) {
      const f16* bslab = (K < 10) ? xs : hcur;
      const int ko = ((K < 10) ? K * 32 : (K - 10) * 32) + kq;
#pragma unroll
      for (int j = 0; j < 2; j++)
        bfx[K][j] = *(const half8*)(bslab + (j * 16 + lr) * HROW + ko);
    }

    // ---- 5 M-chunks of 256 gate rows; pure {A-load, MFMA} inner loop ----
    for (int m = 0; m < 5; ++m) {
      const f16* wrm = wr0 + (size_t)m * 256 * KC;
      const f16* wrn = wr0 + (size_t)((m + 1) % 5) * 256 * KC;
      f32x4 acc[4][2];
#pragma unroll
      for (int i = 0; i < 4; i++)
#pragma unroll
        for (int j = 0; j < 2; j++) acc[i][j] = (f32x4){0.f, 0.f, 0.f, 0.f};

#define KS(K) kstep<K>(wrm, wrn, Ab, bfx, acc);
      KS(0) KS(1) KS(2) KS(3) KS(4) KS(5) KS(6) KS(7) KS(8) KS(9)
      KS(10) KS(11) KS(12) KS(13) KS(14) KS(15) KS(16) KS(17) KS(18) KS(19)
#undef KS

      // ---- gate epilogue for this chunk: c (LDS), h_new -> hnxt ----
#pragma unroll
      for (int i = 0; i < 4; i++) {
        const int jh = m * 64 + wave * 16 + i * 4 + lq;  // 0..319
        const float4 b4 = *(const float4*)&bl[4 * jh];
#pragma unroll
        for (int j = 0; j < 2; j++) {
          const int b = j * 16 + lr;  // 0..31
          float* cp = &cls[jh * 33 + b];
          const float co = *cp;
          const float zi = acc[i][j][0] + b4.x;
          const float zf = acc[i][j][1] + b4.y;
          const float zg = acc[i][j][2] + b4.z;
          const float zo = acc[i][j][3] + b4.w;
          const float cn = sigmoid_(zf) * co + sigmoid_(zi) * tanh_fast(zg);
          *cp = cn;  // pad rows (jh>=300): zero weights/bias -> stays 0
          hnxt[b * HROW + jh] = (f16)(sigmoid_(zo) * tanh_fast(cn));
        }
      }
    }
    __syncthreads();  // hnxt complete

    // ---- hs write-out: rows [b][304] contiguous from hnxt row b ----
    for (int idx = tid; idx < 32 * 38; idx += 256) {
      const int b = idx / 38, ch = idx % 38;  // 38 half8 chunks = 304 f16
      f16* dst = hs + ((size_t)d * B_ + bt * BT + b) * SB2 + t * TR;
      *(half8*)(dst + ch * 8) = *(const half8*)(hnxt + b * HROW + ch * 8);
    }
    // ---- commit prefetched x_{t+1} ----
    if (t + 1 < T_) {
#pragma unroll
      for (int p = 0; p < 5; ++p) *(half8*)(xs + doff[p]) = xn[p];
    }
    __syncthreads();
  }
}

// ---------------------------------------------------------------------------
// attn1: alpha[b][t] = softmax_t( sum_h tanh(hs0+hs1) * conv_w[h] ).
// Pure stream over hs; half4 loads (rows are 304-wide, zero-padded).
// ---------------------------------------------------------------------------
__global__ __launch_bounds__(256) void attn1(const f16* __restrict__ hs,
                                             const float* __restrict__ conv_w,
                                             float* __restrict__ alpha_g) {
  __shared__ float cw[TR];
  __shared__ float red[48];
  const int b = blockIdx.x, tid = threadIdx.x;
  const int wave = tid >> 6, lane = tid & 63;
  for (int k = tid; k < TR; k += 256) cw[k] = (k < H_) ? conv_w[k] : 0.f;
  __syncthreads();

  const half4* s0 = (const half4*)(hs + (size_t)b * SB2);
  const half4* s1 = (const half4*)(hs + (size_t)(B_ + b) * SB2);
  for (int t = wave; t < T_; t += 4) {
    const int base = t * (TR / 4);
    float p = 0.f;
    {
      half4 a = s0[base + lane], cc = s1[base + lane];
#pragma unroll
      for (int r = 0; r < 4; r++)
        p += tanh_fast((float)a[r] + (float)cc[r]) * cw[lane * 4 + r];
    }
    if (lane < 12) {
      half4 a = s0[base + 64 + lane], cc = s1[base + 64 + lane];
#pragma unroll
      for (int r = 0; r < 4; r++)
        p += tanh_fast((float)a[r] + (float)cc[r]) * cw[256 + lane * 4 + r];
    }
#pragma unroll
    for (int o = 32; o; o >>= 1) p += __shfl_down(p, o);
    if (lane == 0) red[t] = p;
  }
  __syncthreads();
  if (tid < 64) {
    float a = (tid < T_) ? red[tid] : -1e30f;
    float mx = a;
#pragma unroll
    for (int o = 32; o; o >>= 1) mx = fmaxf(mx, __shfl_xor(mx, o));
    float e = (tid < T_) ? __expf(a - mx) : 0.f;
    float s = e;
#pragma unroll
    for (int o = 32; o; o >>= 1) s += __shfl_xor(s, o);
    if (tid < T_) alpha_g[(size_t)b * 44 + tid] = e / s;
  }
}

// ---------------------------------------------------------------------------
// attn2: r[b][h] = sum_t hsum*alpha; hstar = tanh(r); logits; softmax.
// Thread-per-h accumulation, coalesced streaming.
// ---------------------------------------------------------------------------
__global__ __launch_bounds__(256) void attn2(const f16* __restrict__ hs,
                                             const float* __restrict__ alpha_g,
                                             const float* __restrict__ fc_w,
                                             const float* __restrict__ fc_b,
                                             float* __restrict__ out) {
  __shared__ float al[T_];
  __shared__ float hstar[TR];
  __shared__ float lg[NC_];
  const int b = blockIdx.x, tid = threadIdx.x;
  if (tid < T_) al[tid] = alpha_g[(size_t)b * 44 + tid];
  __syncthreads();

  const f16* s0 = hs + (size_t)b * SB2;
  const f16* s1 = hs + (size_t)(B_ + b) * SB2;
  float r0 = 0.f, r1 = 0.f;
  for (int t = 0; t < T_; t++) {
    const float a = al[t];
    r0 += ((float)s0[t * TR + tid] + (float)s1[t * TR + tid]) * a;
    if (tid < 48)
      r1 += ((float)s0[t * TR + 256 + tid] + (float)s1[t * TR + 256 + tid]) * a;
  }
  hstar[tid] = tanh_fast(r0);
  if (tid < 48) hstar[256 + tid] = tanh_fast(r1);
  __syncthreads();

  const int wave = tid >> 6, lane = tid & 63;
  for (int cls = wave; cls < NC_; cls += 4) {
    float p = 0.f;
    for (int k = lane; k < H_; k += 64) p += hstar[k] * fc_w[(size_t)cls * H_ + k];
#pragma unroll
    for (int o = 32; o; o >>= 1) p += __shfl_down(p, o);
    if (lane == 0) lg[cls] = p + fc_b[cls];
  }
  __syncthreads();
  if (tid < 64) {
    float a0 = (tid < 40) ? lg[tid] : -1e30f;
    float a1 = (tid < 40) ? lg[tid + 40] : -1e30f;
    float mx = fmaxf(a0, a1);
#pragma unroll
    for (int o = 32; o; o >>= 1) mx = fmaxf(mx, __shfl_xor(mx, o));
    float e0 = (tid < 40) ? __expf(a0 - mx) : 0.f;
    float e1 = (tid < 40) ? __expf(a1 - mx) : 0.f;
    float s = e0 + e1;
#pragma unroll
    for (int o = 32; o; o >>= 1) s += __shfl_xor(s, o);
    if (tid < 40) {
      out[(size_t)b * NC_ + tid] = e0 / s;
      out[(size_t)b * NC_ + tid + 40] = e1 / s;
    }
  }
}

// ---------------------------------------------------------------------------
extern "C" void kernel_launch(void* const* d_in, const int* in_sizes, int n_in,
                              void* d_out, int out_size, void* d_ws, size_t ws_size,
                              hipStream_t stream) {
  const float* x      = (const float*)d_in[0];
  const float* w_ih   = (const float*)d_in[1];
  const float* w_hh   = (const float*)d_in[2];
  const float* b_ih   = (const float*)d_in[3];
  const float* b_hh   = (const float*)d_in[4];
  const float* conv_w = (const float*)d_in[5];
  const float* fc_w   = (const float*)d_in[6];
  const float* fc_b   = (const float*)d_in[7];
  float* out = (float*)d_out;

  // Workspace carve (~331 MB)
  char* p = (char*)d_ws;
  f16* Wcat = (f16*)p;  p += (size_t)NDD * KC * sizeof(f16);        // 3.3 MB
  float* bias = (float*)p; p += (size_t)NDD * sizeof(float);
  p = (char*)(((uintptr_t)p + 255) & ~(uintptr_t)255);
  f16* xT = (f16*)p;    p += (size_t)T_ * B_ * HP * sizeof(f16);    // 112.7 MB
  f16* hs = (f16*)p;    p += (size_t)2 * B_ * SB2 * sizeof(f16);    // 214.2 MB
  float* alpha_g = (float*)p; p += (size_t)B_ * 44 * sizeof(float); // 0.72 MB

  prep_weights<<<(NDD * KC + 255) / 256, 256, 0, stream>>>(
      w_ih, w_hh, b_ih, b_hh, Wcat, bias);
  prep_xT<<<dim3(B_, 5), 256, 0, stream>>>(x, xT);

  lstm_all<<<256, 256, LDS_TOTAL, stream>>>(xT, Wcat, bias, hs);

  attn1<<<B_, 256, 0, stream>>>(hs, conv_w, alpha_g);
  attn2<<<B_, 256, 0, stream>>>(hs, alpha_g, fc_w, fc_b, out);
}